// Round 1
// baseline (190.606 us; speedup 1.0000x reference)
//
#include <hip/hip_runtime.h>
#include <hip/hip_bf16.h>

#define NN 4096
#define LOG2E 1.44269504088896340736f
#define SPLITS 8

typedef __attribute__((ext_vector_type(8))) short s8v;   // 8 x bf16
typedef __attribute__((ext_vector_type(4))) float f4v;   // mfma accumulator

__device__ __forceinline__ unsigned fu(float x){ union{float f;unsigned u;}z; z.f=x; return z.u; }
// pack two floats to bf16x2 by truncation (bias cancels in acc/l ratio)
__device__ __forceinline__ unsigned pack2(float a, float b){
  return __builtin_amdgcn_perm(fu(b), fu(a), 0x07060302u);
}
__device__ __forceinline__ unsigned short f2bf_rne(float x){
  unsigned u = fu(x);
  u += 0x7fffu + ((u >> 16) & 1u);
  return (unsigned short)(u >> 16);
}

// Kernel 1: h = x@W (fp32), write Vt[c][j] (bf16, transposed), el'/er' (x LOG2E)
// block = 256 threads, 8 rows of x per block; thread t owns output column c = t.
__global__ __launch_bounds__(256) void k1_proj(
    const float* __restrict__ x, const float* __restrict__ W,
    const float* __restrict__ a, unsigned short* __restrict__ Vt,
    float* __restrict__ el4, float* __restrict__ erT)
{
  __shared__ float4 xs[512];           // 8 rows x 256 cols fp32
  const int t = threadIdx.x;
  const int r0 = blockIdx.x * 8;
  const float4* xg = (const float4*)(x + (size_t)r0 * 256);
  xs[t] = xg[t];
  xs[t + 256] = xg[t + 256];
  __syncthreads();

  float acc[8] = {0.f,0.f,0.f,0.f,0.f,0.f,0.f,0.f};
  const float* Wp = W + t;             // column c = t
  #pragma unroll 2
  for (int k4 = 0; k4 < 64; ++k4) {
    float w0 = Wp[(k4*4+0)*256];
    float w1 = Wp[(k4*4+1)*256];
    float w2 = Wp[(k4*4+2)*256];
    float w3 = Wp[(k4*4+3)*256];
    #pragma unroll
    for (int r = 0; r < 8; ++r) {
      float4 xv = xs[r*64 + k4];       // broadcast LDS read
      acc[r] = fmaf(xv.x, w0, acc[r]);
      acc[r] = fmaf(xv.y, w1, acc[r]);
      acc[r] = fmaf(xv.z, w2, acc[r]);
      acc[r] = fmaf(xv.w, w3, acc[r]);
    }
  }

  // Vt write: thread t holds 8 consecutive-j values of column c=t -> one 16B store
  union { unsigned u[4]; s8v v; } pk;
  #pragma unroll
  for (int p = 0; p < 4; ++p)
    pk.u[p] = (unsigned)f2bf_rne(acc[2*p]) | ((unsigned)f2bf_rne(acc[2*p+1]) << 16);
  *(s8v*)(Vt + (size_t)t * NN + r0) = pk.v;

  // el/er: wave w == head h; lane f = t&63
  const int f = t & 63, h = t >> 6;
  const float al = a[f], ar = a[64 + f];
  #pragma unroll
  for (int r = 0; r < 8; ++r) {
    float v = acc[r] * al;
    float u = acc[r] * ar;
    #pragma unroll
    for (int off = 32; off > 0; off >>= 1) {
      v += __shfl_xor(v, off);
      u += __shfl_xor(u, off);
    }
    if (f == 0) {
      el4[(r0 + r) * 4 + h] = v * LOG2E;   // [i][h] fp32
      erT[h * NN + (r0 + r)] = u * LOG2E;  // [h][j] fp32
    }
  }
}

// Kernel 2: fused mask+lrelu+exp + PV GEMM via MFMA, per-head acc + l partials.
// grid (64 i-tiles, SPLITS j-chunks), block 256 = 4 waves; wave w owns rows
// i0+16w..+15, all 4 heads; lane: m = l&15 (row), q = l>>4 (k-quad).
__global__ __launch_bounds__(256, 2) void k2_attn(
    const float* __restrict__ adj, const unsigned short* __restrict__ Vt,
    const float* __restrict__ el4, const float* __restrict__ erT,
    float* __restrict__ accP, float* __restrict__ lP)
{
  const int t = threadIdx.x;
  const int w = t >> 6, l = t & 63;
  const int m = l & 15, q = l >> 4;
  const int i0 = blockIdx.x * 64;
  const int split = blockIdx.y;
  const int i = i0 + w * 16 + m;

  float4 elv4 = *(const float4*)(el4 + i * 4);
  float elv[4] = {elv4.x, elv4.y, elv4.z, elv4.w};

  f4v acc[4][4];
  #pragma unroll
  for (int h = 0; h < 4; ++h)
    #pragma unroll
    for (int nf = 0; nf < 4; ++nf)
      acc[h][nf] = (f4v){0.f, 0.f, 0.f, 0.f};
  float lsum[4] = {0.f, 0.f, 0.f, 0.f};

  const float* arow = adj + (size_t)i * NN;
  int j0 = split * 512 + q * 8;

  #pragma unroll 1
  for (int jc = 0; jc < 16; ++jc, j0 += 32) {
    float4 a0 = *(const float4*)(arow + j0);
    float4 a1 = *(const float4*)(arow + j0 + 4);
    #pragma unroll
    for (int h = 0; h < 4; ++h) {
      float4 e0 = *(const float4*)(erT + h * NN + j0);
      float4 e1 = *(const float4*)(erT + h * NN + j0 + 4);
      const float eh = elv[h];
      float t0 = eh + e0.x, t1 = eh + e0.y, t2 = eh + e0.z, t3 = eh + e0.w;
      float t4 = eh + e1.x, t5 = eh + e1.y, t6 = eh + e1.z, t7 = eh + e1.w;
      // s = adj * exp(lrelu(el+er)); inputs pre-scaled by LOG2E
      float s0 = a0.x * __builtin_amdgcn_exp2f(fmaxf(t0, 0.2f*t0));
      float s1 = a0.y * __builtin_amdgcn_exp2f(fmaxf(t1, 0.2f*t1));
      float s2 = a0.z * __builtin_amdgcn_exp2f(fmaxf(t2, 0.2f*t2));
      float s3 = a0.w * __builtin_amdgcn_exp2f(fmaxf(t3, 0.2f*t3));
      float s4 = a1.x * __builtin_amdgcn_exp2f(fmaxf(t4, 0.2f*t4));
      float s5 = a1.y * __builtin_amdgcn_exp2f(fmaxf(t5, 0.2f*t5));
      float s6 = a1.z * __builtin_amdgcn_exp2f(fmaxf(t6, 0.2f*t6));
      float s7 = a1.w * __builtin_amdgcn_exp2f(fmaxf(t7, 0.2f*t7));
      lsum[h] += ((s0+s1)+(s2+s3)) + ((s4+s5)+(s6+s7));
      union { unsigned u[4]; s8v v; } A;   // A-frag: row m, k = q*8+idx
      A.u[0] = pack2(s0, s1);
      A.u[1] = pack2(s2, s3);
      A.u[2] = pack2(s4, s5);
      A.u[3] = pack2(s6, s7);
      const unsigned short* vb = Vt + (size_t)(h * 64 + m) * NN + j0;
      #pragma unroll
      for (int nf = 0; nf < 4; ++nf) {
        s8v B = *(const s8v*)(vb + (size_t)nf * 16 * NN);  // B-frag: col n=m, k=q*8+idx
        acc[h][nf] = __builtin_amdgcn_mfma_f32_16x16x32_bf16(A.v, B, acc[h][nf], 0, 0, 0);
      }
    }
  }

  // l: reduce over the 4 k-quads holding the same row (lanes m, m+16, m+32, m+48)
  #pragma unroll
  for (int h = 0; h < 4; ++h) {
    float v = lsum[h];
    v += __shfl_xor(v, 16);
    v += __shfl_xor(v, 32);
    lsum[h] = v;
  }
  if (l < 16) {
    int row = i0 + w * 16 + l;
    float4 lv = make_float4(lsum[0], lsum[1], lsum[2], lsum[3]);
    *(float4*)(lP + ((size_t)split * NN + row) * 4) = lv;
  }
  // C/D layout: col = l&15, row = q*4 + reg
  float* ap = accP + (size_t)split * NN * 256;
  #pragma unroll
  for (int h = 0; h < 4; ++h)
    #pragma unroll
    for (int nf = 0; nf < 4; ++nf)
      #pragma unroll
      for (int r = 0; r < 4; ++r) {
        int row = i0 + w * 16 + q * 4 + r;
        int col = h * 64 + nf * 16 + m;
        ap[(size_t)row * 256 + col] = acc[h][nf][r];
      }
}

// Kernel 3: combine split partials, divide by l, mean over heads.
__global__ __launch_bounds__(256) void k3_reduce(
    const float* __restrict__ accP, const float* __restrict__ lP,
    float* __restrict__ out)
{
  int tid = blockIdx.x * 256 + threadIdx.x;  // 262144 threads
  int i = tid >> 6, f = tid & 63;
  float o = 0.f;
  #pragma unroll
  for (int h = 0; h < 4; ++h) {
    float sa = 0.f, sl = 0.f;
    #pragma unroll
    for (int s = 0; s < SPLITS; ++s) {
      sa += accP[((size_t)s * NN + i) * 256 + h * 64 + f];
      sl += lP[((size_t)s * NN + i) * 4 + h];
    }
    o += sa / sl;   // sl > 0 guaranteed: diagonal of adj is 1
  }
  out[tid] = 0.25f * o;
}

extern "C" void kernel_launch(void* const* d_in, const int* in_sizes, int n_in,
                              void* d_out, int out_size, void* d_ws, size_t ws_size,
                              hipStream_t stream) {
  const float* x   = (const float*)d_in[0];   // (4096, 256)
  const float* adj = (const float*)d_in[1];   // (4096, 4096)
  const float* W   = (const float*)d_in[2];   // (256, 256)
  const float* a   = (const float*)d_in[3];   // (128, 1)
  float* out = (float*)d_out;                 // (4096, 64)

  char* ws = (char*)d_ws;
  unsigned short* Vt = (unsigned short*)ws;                       // 2 MB  bf16 [256][4096]
  float* el4 = (float*)(ws + (2u << 20));                         // 64 KB [4096][4]
  float* erT = (float*)(ws + (2u << 20) + (64u << 10));           // 64 KB [4][4096]
  float* lP  = (float*)(ws + (2u << 20) + (128u << 10));          // 512 KB [8][4096][4]
  float* accP= (float*)(ws + (2u << 20) + (128u << 10) + (512u << 10)); // 32 MB [8][4096][256]

  k1_proj<<<512, 256, 0, stream>>>(x, W, a, Vt, el4, erT);
  k2_attn<<<dim3(64, SPLITS), 256, 0, stream>>>(adj, Vt, el4, erT, accP, lP);
  k3_reduce<<<1024, 256, 0, stream>>>(accP, lP, out);
}